// Round 4
// baseline (135.734 us; speedup 1.0000x reference)
//
#include <hip/hip_runtime.h>

// Problem constants (fixed by reference)
constexpr int N_AG = 4096;   // N agents
constexpr int M_CL = 256;    // M clusters
constexpr int KD   = 32;     // K dim
constexpr float WEPS = 1e-6f;

constexpr int P_SPLIT = 4;            // n-splits per cluster in partial kernel
constexpr int PART_STRIDE = 1088;     // floats per (m,p) partial record: [S2(1024) | S1(32) | Z | count | pad]
constexpr int V_OFF  = M_CL * P_SPLIT * PART_STRIDE;  // v (4096x32) at ws+V_OFF
constexpr int WT_OFF = V_OFF + N_AG * KD;             // Wt (256x4096, masked) at ws+WT_OFF
// total ws use: 1,114,112 + 131,072 + 1,048,576 floats = 9.2 MB

__device__ __forceinline__ float rlane(float x, int l) {
    return __int_as_float(__builtin_amdgcn_readlane(__float_as_int(x), l));
}

// ---------------------------------------------------------------------------
// K0: transpose + mask W: Wt[m][n] = (W[n][m] >= WEPS) ? W[n][m] : 0
// 32x32 LDS tiles; coalesced both directions.
// ---------------------------------------------------------------------------
__global__ __launch_bounds__(256) void transpose_kernel(const float* __restrict__ W,
                                                        float* __restrict__ Wt) {
    __shared__ float tb[32][33];
    const int x  = threadIdx.x & 31;
    const int y  = threadIdx.x >> 5;          // 0..7
    const int n0 = (blockIdx.x & 127) * 32;   // 4096/32 = 128 n-tiles
    const int m0 = (blockIdx.x >> 7) * 32;    // 256/32  = 8 m-tiles
    #pragma unroll
    for (int r = 0; r < 4; ++r) {
        const int n = y + 8 * r;
        float w = W[(size_t)(n0 + n) * 256 + m0 + x];
        tb[n][x] = (w >= WEPS) ? w : 0.0f;
    }
    __syncthreads();
    #pragma unroll
    for (int r = 0; r < 4; ++r) {
        const int mm = y + 8 * r;
        Wt[(size_t)(m0 + mm) * 4096 + n0 + x] = tb[x][mm];
    }
}

// ---------------------------------------------------------------------------
// K1: batched 32x32 SPD solve  v_n = omega_child_n^{-1} mu_n
// One wave per matrix; lane c owns column c (c=32 -> rhs). Gauss-Jordan with
// pivot broadcast via v_readlane (static reg indexing via full unroll).
// ---------------------------------------------------------------------------
__global__ __launch_bounds__(256) void solve_kernel(const float* __restrict__ oc,
                                                    const float* __restrict__ mu,
                                                    float* __restrict__ v) {
    const int lane = threadIdx.x & 63;
    const int wid  = threadIdx.x >> 6;
    const int idx  = blockIdx.x * 4 + wid;   // matrix id, 0..4095

    const int c = (lane < 32) ? lane : 32;   // lanes 33..63 mirror the rhs (harmless)

    float col[32];
    #pragma unroll
    for (int i = 0; i < 32; ++i) {
        col[i] = (c < 32) ? oc[idx * 1024 + i * 32 + c]
                          : mu[idx * 32 + i];
    }

    #pragma unroll
    for (int j = 0; j < 32; ++j) {
        const float piv  = rlane(col[j], j);
        const float pinv = 1.0f / piv;
        col[j] *= pinv;
        #pragma unroll
        for (int i = 0; i < 32; ++i) {
            if (i == j) continue;
            const float fi = rlane(col[i], j);
            col[i] = fmaf(-fi, col[j], col[i]);
        }
    }

    float res = 0.0f;
    #pragma unroll
    for (int i = 0; i < 32; ++i) {
        const float xi = rlane(col[i], 32);
        if (lane == i) res = xi;
    }
    if (lane < 32) v[idx * 32 + lane] = res;
}

// ---------------------------------------------------------------------------
// K2: partial weighted moments per (m, part).
//   S2 = sum_n w*v v^T, S1 = sum_n w*v, Z = sum w, count = sum (w>=eps)
// grid = 1024 blocks (m = bid>>2, p = bid&3), 256 threads.
// Thread owns an 8x8 S2 tile over 1/16 of n (sub); 16 sub-partials reduced
// at block end through vbuf staging (4 rounds).
// ROUND-4: launch_bounds (256,2)->(256,4). Round-3 profile: VALUBusy 40%,
// occupancy 21% (2 blocks/CU, self-inflicted). VALU work = 13.7 us, LDS
// work = ~14 us (1 B ds_read per FMA = exactly the 128B/cyc : 128FMA/cyc
// CU ratio) -> both pipes half-idle purely from low occupancy. VGPR 68
// fits the 128-reg cap of 4 waves/EU; LDS 24KBx4=94KB < 160KB.
// ---------------------------------------------------------------------------
__global__ __launch_bounds__(256, 4) void partial_kernel(const float* __restrict__ Wt,
                                                         const float* __restrict__ v,
                                                         float* __restrict__ wsout) {
    const int m = blockIdx.x >> 2;
    const int p = blockIdx.x & 3;
    const int t = threadIdx.x;

    __shared__ float vbuf[128 * 36];   // stride 36: <=2-way banks; reused as reduction stage
    __shared__ float wbuf[1024];       // masked weights for this (m,p)
    __shared__ float s1buf[32];
    __shared__ float red[256];

    const int tile = t & 15;
    const int sub  = t >> 4;
    const int k0 = (tile >> 2) * 8;
    const int l0 = (tile & 3) * 8;
    const bool do_s1 = ((tile & 3) == 0);

    // ---- W phase: 1024 masked weights, coalesced float4 ----
    float zacc = 0.0f, cacc = 0.0f;
    {
        const float4 wv = reinterpret_cast<const float4*>(Wt + (size_t)m * 4096 + p * 1024)[t];
        zacc = wv.x + wv.y + wv.z + wv.w;
        cacc = (wv.x >= WEPS ? 1.f : 0.f) + (wv.y >= WEPS ? 1.f : 0.f)
             + (wv.z >= WEPS ? 1.f : 0.f) + (wv.w >= WEPS ? 1.f : 0.f);
        *reinterpret_cast<float4*>(&wbuf[t * 4]) = wv;
    }

    float acc[8][8];
    #pragma unroll
    for (int r = 0; r < 8; ++r)
        #pragma unroll
        for (int cc = 0; cc < 8; ++cc) acc[r][cc] = 0.0f;
    float s1acc[8] = {0.f,0.f,0.f,0.f,0.f,0.f,0.f,0.f};

    for (int ch = 0; ch < 8; ++ch) {
        const int n0 = p * 1024 + ch * 128;
        // stage 128x32 v values: coalesced float4 global loads
        const float4* vg4 = reinterpret_cast<const float4*>(v + (size_t)n0 * 32);
        #pragma unroll
        for (int i = 0; i < 4; ++i) {
            const int g4 = t + 256 * i;            // 0..1023 float4s
            const int nc = g4 >> 3, cc4 = (g4 & 7) * 4;
            *reinterpret_cast<float4*>(&vbuf[nc * 36 + cc4]) = vg4[g4];
        }
        __syncthreads();

        const float4* vb4 = reinterpret_cast<const float4*>(vbuf);
        #pragma unroll 2
        for (int i = 0; i < 8; ++i) {
            const int nc = sub + 16 * i;
            const float w = wbuf[ch * 128 + nc];
            const float4 a0 = vb4[nc * 9 + (k0 >> 2)];
            const float4 a1 = vb4[nc * 9 + (k0 >> 2) + 1];
            const float4 b0 = vb4[nc * 9 + (l0 >> 2)];
            const float4 b1 = vb4[nc * 9 + (l0 >> 2) + 1];
            float wa[8] = {w*a0.x, w*a0.y, w*a0.z, w*a0.w,
                           w*a1.x, w*a1.y, w*a1.z, w*a1.w};
            const float bb[8] = {b0.x, b0.y, b0.z, b0.w, b1.x, b1.y, b1.z, b1.w};
            #pragma unroll
            for (int r = 0; r < 8; ++r)
                #pragma unroll
                for (int cc = 0; cc < 8; ++cc)
                    acc[r][cc] = fmaf(wa[r], bb[cc], acc[r][cc]);
            if (do_s1) {
                #pragma unroll
                for (int r = 0; r < 8; ++r) s1acc[r] += wa[r];
            }
        }
        __syncthreads();
    }

    // ---- epilogue 1: reduce 16 sub-partials per tile through vbuf stage ----
    const size_t base = (size_t)(m * 4 + p) * PART_STRIDE;
    const int sslot = sub & 3;
    const int k   = t >> 3;          // owned output row
    const int l0p = (t & 7) * 4;     // owned output col start
    const int eoff = ((k >> 3) * 4 + (l0p >> 3)) * 68 + (k & 7) * 8 + (l0p & 7);
    float fin0 = 0.f, fin1 = 0.f, fin2 = 0.f, fin3 = 0.f;

    #pragma unroll
    for (int r4 = 0; r4 < 4; ++r4) {
        if ((t >> 6) == r4) {
            float* dst = &vbuf[sslot * 1088 + tile * 68];
            #pragma unroll
            for (int r = 0; r < 8; ++r) {
                *reinterpret_cast<float4*>(&dst[r * 8])     =
                    make_float4(acc[r][0], acc[r][1], acc[r][2], acc[r][3]);
                *reinterpret_cast<float4*>(&dst[r * 8 + 4]) =
                    make_float4(acc[r][4], acc[r][5], acc[r][6], acc[r][7]);
            }
        }
        __syncthreads();
        #pragma unroll
        for (int s = 0; s < 4; ++s) {
            const float4 vv = *reinterpret_cast<const float4*>(&vbuf[s * 1088 + eoff]);
            fin0 += vv.x; fin1 += vv.y; fin2 += vv.z; fin3 += vv.w;
        }
        __syncthreads();
    }
    *reinterpret_cast<float4*>(&wsout[base + k * 32 + l0p]) =
        make_float4(fin0, fin1, fin2, fin3);

    // ---- epilogue 2: S1 / Z / count ----
    if (t < 32) s1buf[t] = 0.0f;
    __syncthreads();
    if (do_s1) {
        #pragma unroll
        for (int r = 0; r < 8; ++r) atomicAdd(&s1buf[k0 + r], s1acc[r]);
    }

    red[t] = zacc; __syncthreads();
    #pragma unroll
    for (int s = 128; s > 0; s >>= 1) {
        if (t < s) red[t] += red[t + s];
        __syncthreads();
    }
    if (t == 0) wsout[base + 1056] = red[0];
    __syncthreads();

    red[t] = cacc; __syncthreads();
    #pragma unroll
    for (int s = 128; s > 0; s >>= 1) {
        if (t < s) red[t] += red[t + s];
        __syncthreads();
    }
    if (t == 0) wsout[base + 1057] = red[0];

    if (t < 32) wsout[base + 1024 + t] = s1buf[t];
}

// ---------------------------------------------------------------------------
// K3: combine. One block per m.
//   G = Omega_parent^T Omega_parent ; psi = tr(G S2)/Z - vbar^T G vbar
// ---------------------------------------------------------------------------
__global__ __launch_bounds__(256) void combine_kernel(const float* __restrict__ op,
                                                      const float* __restrict__ ws,
                                                      float* __restrict__ out) {
    const int m = blockIdx.x;
    const int t = threadIdx.x;

    __shared__ float omg[32 * 33];
    __shared__ float vbar[32];
    __shared__ float red[256];

    #pragma unroll
    for (int i = 0; i < 4; ++i) {
        const int g = t + 256 * i;
        const int r = g >> 5, cc = g & 31;
        omg[r * 33 + cc] = op[(size_t)m * 1024 + g];
    }

    const size_t mb = (size_t)m * 4 * PART_STRIDE;
    float Z = 0.0f, cnt = 0.0f, s1 = 0.0f;
    float s2[4] = {0.f, 0.f, 0.f, 0.f};
    #pragma unroll
    for (int p2 = 0; p2 < 4; ++p2) {
        const size_t bp = mb + (size_t)p2 * PART_STRIDE;
        Z   += ws[bp + 1056];
        cnt += ws[bp + 1057];
        if (t < 32) s1 += ws[bp + 1024 + t];
        const float4 sp = *reinterpret_cast<const float4*>(&ws[bp + t * 4]);
        s2[0] += sp.x; s2[1] += sp.y; s2[2] += sp.z; s2[3] += sp.w;
    }
    const float invZ = 1.0f / fmaxf(Z, 1e-30f);
    if (t < 32) vbar[t] = s1 * invZ;
    __syncthreads();

    const int k  = t >> 3;
    const int l0 = (t & 7) * 4;
    float G[4] = {0.f, 0.f, 0.f, 0.f};
    #pragma unroll
    for (int i = 0; i < 32; ++i) {
        const float ok = omg[i * 33 + k];
        #pragma unroll
        for (int q = 0; q < 4; ++q) G[q] = fmaf(ok, omg[i * 33 + l0 + q], G[q]);
    }

    const float vk = vbar[k];
    float val = 0.0f;
    #pragma unroll
    for (int q = 0; q < 4; ++q)
        val += G[q] * (s2[q] * invZ - vk * vbar[l0 + q]);

    red[t] = val; __syncthreads();
    #pragma unroll
    for (int s = 128; s > 0; s >>= 1) {
        if (t < s) red[t] += red[t + s];
        __syncthreads();
    }
    if (t == 0) out[m] = (cnt >= 1.5f) ? red[0] : 0.0f;
}

// ---------------------------------------------------------------------------
extern "C" void kernel_launch(void* const* d_in, const int* in_sizes, int n_in,
                              void* d_out, int out_size, void* d_ws, size_t ws_size,
                              hipStream_t stream) {
    const float* W  = (const float*)d_in[0];  // (4096, 256)
    const float* mu = (const float*)d_in[1];  // (4096, 32)
    const float* oc = (const float*)d_in[2];  // (4096, 32, 32)
    const float* op = (const float*)d_in[3];  // (256, 32, 32)
    float* out = (float*)d_out;               // (256,)
    float* ws  = (float*)d_ws;

    transpose_kernel<<<1024, 256, 0, stream>>>(W, ws + WT_OFF);
    solve_kernel<<<1024, 256, 0, stream>>>(oc, mu, ws + V_OFF);
    partial_kernel<<<1024, 256, 0, stream>>>(ws + WT_OFF, ws + V_OFF, ws);
    combine_kernel<<<256, 256, 0, stream>>>(op, ws, out);
}

// Round 5
// 134.931 us; speedup vs baseline: 1.0060x; 1.0060x over previous
//
#include <hip/hip_runtime.h>

// Problem constants (fixed by reference)
constexpr int N_AG = 4096;   // N agents
constexpr int M_CL = 256;    // M clusters
constexpr int KD   = 32;     // K dim
constexpr float WEPS = 1e-6f;

constexpr int P_SPLIT = 4;            // n-splits per cluster in partial kernel
constexpr int PART_STRIDE = 1088;     // floats per (m,p) partial record: [S2(1024) | S1(32) | Z | count | pad]
constexpr int V_OFF  = M_CL * P_SPLIT * PART_STRIDE;  // v (4096x32) at ws+V_OFF
constexpr int WT_OFF = V_OFF + N_AG * KD;             // Wt (256x4096, masked) at ws+WT_OFF
// total ws use: 1,114,112 + 131,072 + 1,048,576 floats = 9.2 MB

__device__ __forceinline__ float rlane(float x, int l) {
    return __int_as_float(__builtin_amdgcn_readlane(__float_as_int(x), l));
}

// ---------------------------------------------------------------------------
// K0: transpose + mask W: Wt[m][n] = (W[n][m] >= WEPS) ? W[n][m] : 0
// 32x32 LDS tiles; coalesced both directions.
// ---------------------------------------------------------------------------
__global__ __launch_bounds__(256) void transpose_kernel(const float* __restrict__ W,
                                                        float* __restrict__ Wt) {
    __shared__ float tb[32][33];
    const int x  = threadIdx.x & 31;
    const int y  = threadIdx.x >> 5;          // 0..7
    const int n0 = (blockIdx.x & 127) * 32;   // 4096/32 = 128 n-tiles
    const int m0 = (blockIdx.x >> 7) * 32;    // 256/32  = 8 m-tiles
    #pragma unroll
    for (int r = 0; r < 4; ++r) {
        const int n = y + 8 * r;
        float w = W[(size_t)(n0 + n) * 256 + m0 + x];
        tb[n][x] = (w >= WEPS) ? w : 0.0f;
    }
    __syncthreads();
    #pragma unroll
    for (int r = 0; r < 4; ++r) {
        const int mm = y + 8 * r;
        Wt[(size_t)(m0 + mm) * 4096 + n0 + x] = tb[x][mm];
    }
}

// ---------------------------------------------------------------------------
// K1: batched 32x32 SPD solve  v_n = omega_child_n^{-1} mu_n
// One wave per matrix; lane c owns column c (c=32 -> rhs). Gauss-Jordan with
// pivot broadcast via v_readlane (static reg indexing via full unroll).
// ROUND-5 FIX: bare __launch_bounds__(256) let the backend's occupancy
// heuristic pick a tiny VGPR budget -> VGPR_Count=24, col[32] spilled to
// scratch (invisible in FETCH/WRITE: ~64KB/CU scratch lives in L1/L2),
// 50us instead of the ~7us issue-bound floor, VALUBusy 30%. This kernel is
// wave-count-limited (4096 waves = 4/SIMD max) so occupancy above 4 waves
// is worthless: declare (256,1) -> VGPR cap 512 -> col[] stays in regs.
// ---------------------------------------------------------------------------
__global__ __launch_bounds__(256, 1) void solve_kernel(const float* __restrict__ oc,
                                                       const float* __restrict__ mu,
                                                       float* __restrict__ v) {
    const int lane = threadIdx.x & 63;
    const int wid  = threadIdx.x >> 6;
    const int idx  = blockIdx.x * 4 + wid;   // matrix id, 0..4095

    const int c = (lane < 32) ? lane : 32;   // lanes 33..63 mirror the rhs (harmless)

    float col[32];
    #pragma unroll
    for (int i = 0; i < 32; ++i) {
        col[i] = (c < 32) ? oc[idx * 1024 + i * 32 + c]
                          : mu[idx * 32 + i];
    }

    #pragma unroll
    for (int j = 0; j < 32; ++j) {
        const float piv  = rlane(col[j], j);
        const float pinv = 1.0f / piv;
        col[j] *= pinv;
        #pragma unroll
        for (int i = 0; i < 32; ++i) {
            if (i == j) continue;
            const float fi = rlane(col[i], j);
            col[i] = fmaf(-fi, col[j], col[i]);
        }
    }

    float res = 0.0f;
    #pragma unroll
    for (int i = 0; i < 32; ++i) {
        const float xi = rlane(col[i], 32);
        if (lane == i) res = xi;
    }
    if (lane < 32) v[idx * 32 + lane] = res;
}

// ---------------------------------------------------------------------------
// K2: partial weighted moments per (m, part).
//   S2 = sum_n w*v v^T, S1 = sum_n w*v, Z = sum w, count = sum (w>=eps)
// grid = 1024 blocks (m = bid>>2, p = bid&3), 256 threads.
// Thread owns an 8x8 S2 tile over 1/16 of n (sub); 16 sub-partials reduced
// at block end through vbuf staging (4 rounds).
// launch_bounds (256,4): round-3 profile showed VALUBusy 40% at 2 blocks/CU
// (self-inflicted by (256,2)); VALU and LDS pipes each ~14us of work.
// ---------------------------------------------------------------------------
__global__ __launch_bounds__(256, 4) void partial_kernel(const float* __restrict__ Wt,
                                                         const float* __restrict__ v,
                                                         float* __restrict__ wsout) {
    const int m = blockIdx.x >> 2;
    const int p = blockIdx.x & 3;
    const int t = threadIdx.x;

    __shared__ float vbuf[128 * 36];   // stride 36: <=2-way banks; reused as reduction stage
    __shared__ float wbuf[1024];       // masked weights for this (m,p)
    __shared__ float s1buf[32];
    __shared__ float red[256];

    const int tile = t & 15;
    const int sub  = t >> 4;
    const int k0 = (tile >> 2) * 8;
    const int l0 = (tile & 3) * 8;
    const bool do_s1 = ((tile & 3) == 0);

    // ---- W phase: 1024 masked weights, coalesced float4 ----
    float zacc = 0.0f, cacc = 0.0f;
    {
        const float4 wv = reinterpret_cast<const float4*>(Wt + (size_t)m * 4096 + p * 1024)[t];
        zacc = wv.x + wv.y + wv.z + wv.w;
        cacc = (wv.x >= WEPS ? 1.f : 0.f) + (wv.y >= WEPS ? 1.f : 0.f)
             + (wv.z >= WEPS ? 1.f : 0.f) + (wv.w >= WEPS ? 1.f : 0.f);
        *reinterpret_cast<float4*>(&wbuf[t * 4]) = wv;
    }

    float acc[8][8];
    #pragma unroll
    for (int r = 0; r < 8; ++r)
        #pragma unroll
        for (int cc = 0; cc < 8; ++cc) acc[r][cc] = 0.0f;
    float s1acc[8] = {0.f,0.f,0.f,0.f,0.f,0.f,0.f,0.f};

    for (int ch = 0; ch < 8; ++ch) {
        const int n0 = p * 1024 + ch * 128;
        // stage 128x32 v values: coalesced float4 global loads
        const float4* vg4 = reinterpret_cast<const float4*>(v + (size_t)n0 * 32);
        #pragma unroll
        for (int i = 0; i < 4; ++i) {
            const int g4 = t + 256 * i;            // 0..1023 float4s
            const int nc = g4 >> 3, cc4 = (g4 & 7) * 4;
            *reinterpret_cast<float4*>(&vbuf[nc * 36 + cc4]) = vg4[g4];
        }
        __syncthreads();

        const float4* vb4 = reinterpret_cast<const float4*>(vbuf);
        #pragma unroll 2
        for (int i = 0; i < 8; ++i) {
            const int nc = sub + 16 * i;
            const float w = wbuf[ch * 128 + nc];
            const float4 a0 = vb4[nc * 9 + (k0 >> 2)];
            const float4 a1 = vb4[nc * 9 + (k0 >> 2) + 1];
            const float4 b0 = vb4[nc * 9 + (l0 >> 2)];
            const float4 b1 = vb4[nc * 9 + (l0 >> 2) + 1];
            float wa[8] = {w*a0.x, w*a0.y, w*a0.z, w*a0.w,
                           w*a1.x, w*a1.y, w*a1.z, w*a1.w};
            const float bb[8] = {b0.x, b0.y, b0.z, b0.w, b1.x, b1.y, b1.z, b1.w};
            #pragma unroll
            for (int r = 0; r < 8; ++r)
                #pragma unroll
                for (int cc = 0; cc < 8; ++cc)
                    acc[r][cc] = fmaf(wa[r], bb[cc], acc[r][cc]);
            if (do_s1) {
                #pragma unroll
                for (int r = 0; r < 8; ++r) s1acc[r] += wa[r];
            }
        }
        __syncthreads();
    }

    // ---- epilogue 1: reduce 16 sub-partials per tile through vbuf stage ----
    const size_t base = (size_t)(m * 4 + p) * PART_STRIDE;
    const int sslot = sub & 3;
    const int k   = t >> 3;          // owned output row
    const int l0p = (t & 7) * 4;     // owned output col start
    const int eoff = ((k >> 3) * 4 + (l0p >> 3)) * 68 + (k & 7) * 8 + (l0p & 7);
    float fin0 = 0.f, fin1 = 0.f, fin2 = 0.f, fin3 = 0.f;

    #pragma unroll
    for (int r4 = 0; r4 < 4; ++r4) {
        if ((t >> 6) == r4) {
            float* dst = &vbuf[sslot * 1088 + tile * 68];
            #pragma unroll
            for (int r = 0; r < 8; ++r) {
                *reinterpret_cast<float4*>(&dst[r * 8])     =
                    make_float4(acc[r][0], acc[r][1], acc[r][2], acc[r][3]);
                *reinterpret_cast<float4*>(&dst[r * 8 + 4]) =
                    make_float4(acc[r][4], acc[r][5], acc[r][6], acc[r][7]);
            }
        }
        __syncthreads();
        #pragma unroll
        for (int s = 0; s < 4; ++s) {
            const float4 vv = *reinterpret_cast<const float4*>(&vbuf[s * 1088 + eoff]);
            fin0 += vv.x; fin1 += vv.y; fin2 += vv.z; fin3 += vv.w;
        }
        __syncthreads();
    }
    *reinterpret_cast<float4*>(&wsout[base + k * 32 + l0p]) =
        make_float4(fin0, fin1, fin2, fin3);

    // ---- epilogue 2: S1 / Z / count ----
    if (t < 32) s1buf[t] = 0.0f;
    __syncthreads();
    if (do_s1) {
        #pragma unroll
        for (int r = 0; r < 8; ++r) atomicAdd(&s1buf[k0 + r], s1acc[r]);
    }

    red[t] = zacc; __syncthreads();
    #pragma unroll
    for (int s = 128; s > 0; s >>= 1) {
        if (t < s) red[t] += red[t + s];
        __syncthreads();
    }
    if (t == 0) wsout[base + 1056] = red[0];
    __syncthreads();

    red[t] = cacc; __syncthreads();
    #pragma unroll
    for (int s = 128; s > 0; s >>= 1) {
        if (t < s) red[t] += red[t + s];
        __syncthreads();
    }
    if (t == 0) wsout[base + 1057] = red[0];

    if (t < 32) wsout[base + 1024 + t] = s1buf[t];
}

// ---------------------------------------------------------------------------
// K3: combine. One block per m.
//   G = Omega_parent^T Omega_parent ; psi = tr(G S2)/Z - vbar^T G vbar
// ---------------------------------------------------------------------------
__global__ __launch_bounds__(256) void combine_kernel(const float* __restrict__ op,
                                                      const float* __restrict__ ws,
                                                      float* __restrict__ out) {
    const int m = blockIdx.x;
    const int t = threadIdx.x;

    __shared__ float omg[32 * 33];
    __shared__ float vbar[32];
    __shared__ float red[256];

    #pragma unroll
    for (int i = 0; i < 4; ++i) {
        const int g = t + 256 * i;
        const int r = g >> 5, cc = g & 31;
        omg[r * 33 + cc] = op[(size_t)m * 1024 + g];
    }

    const size_t mb = (size_t)m * 4 * PART_STRIDE;
    float Z = 0.0f, cnt = 0.0f, s1 = 0.0f;
    float s2[4] = {0.f, 0.f, 0.f, 0.f};
    #pragma unroll
    for (int p2 = 0; p2 < 4; ++p2) {
        const size_t bp = mb + (size_t)p2 * PART_STRIDE;
        Z   += ws[bp + 1056];
        cnt += ws[bp + 1057];
        if (t < 32) s1 += ws[bp + 1024 + t];
        const float4 sp = *reinterpret_cast<const float4*>(&ws[bp + t * 4]);
        s2[0] += sp.x; s2[1] += sp.y; s2[2] += sp.z; s2[3] += sp.w;
    }
    const float invZ = 1.0f / fmaxf(Z, 1e-30f);
    if (t < 32) vbar[t] = s1 * invZ;
    __syncthreads();

    const int k  = t >> 3;
    const int l0 = (t & 7) * 4;
    float G[4] = {0.f, 0.f, 0.f, 0.f};
    #pragma unroll
    for (int i = 0; i < 32; ++i) {
        const float ok = omg[i * 33 + k];
        #pragma unroll
        for (int q = 0; q < 4; ++q) G[q] = fmaf(ok, omg[i * 33 + l0 + q], G[q]);
    }

    const float vk = vbar[k];
    float val = 0.0f;
    #pragma unroll
    for (int q = 0; q < 4; ++q)
        val += G[q] * (s2[q] * invZ - vk * vbar[l0 + q]);

    red[t] = val; __syncthreads();
    #pragma unroll
    for (int s = 128; s > 0; s >>= 1) {
        if (t < s) red[t] += red[t + s];
        __syncthreads();
    }
    if (t == 0) out[m] = (cnt >= 1.5f) ? red[0] : 0.0f;
}

// ---------------------------------------------------------------------------
extern "C" void kernel_launch(void* const* d_in, const int* in_sizes, int n_in,
                              void* d_out, int out_size, void* d_ws, size_t ws_size,
                              hipStream_t stream) {
    const float* W  = (const float*)d_in[0];  // (4096, 256)
    const float* mu = (const float*)d_in[1];  // (4096, 32)
    const float* oc = (const float*)d_in[2];  // (4096, 32, 32)
    const float* op = (const float*)d_in[3];  // (256, 32, 32)
    float* out = (float*)d_out;               // (256,)
    float* ws  = (float*)d_ws;

    transpose_kernel<<<1024, 256, 0, stream>>>(W, ws + WT_OFF);
    solve_kernel<<<1024, 256, 0, stream>>>(oc, mu, ws + V_OFF);
    partial_kernel<<<1024, 256, 0, stream>>>(ws + WT_OFF, ws + V_OFF, ws);
    combine_kernel<<<256, 256, 0, stream>>>(op, ws, out);
}

// Round 6
// 115.493 us; speedup vs baseline: 1.1753x; 1.1683x over previous
//
#include <hip/hip_runtime.h>

// Problem constants (fixed by reference)
constexpr int N_AG = 4096;   // N agents
constexpr int M_CL = 256;    // M clusters
constexpr int KD   = 32;     // K dim
constexpr float WEPS = 1e-6f;

// ws layout (floats)
constexpr int PART_STRIDE = 1088;                 // [S2(1024) | S1(32) | Z | count | pad]
constexpr int V_OFF  = M_CL * 4 * PART_STRIDE;    // v  (4096 x 32) n-major
constexpr int VT_OFF = V_OFF + N_AG * KD;         // vT (32 x 4096) k-major
constexpr int WT_OFF = VT_OFF + N_AG * KD;        // Wt (256 x 4096) masked
// total: 1,114,112 + 131,072 + 131,072 + 1,048,576 = 2,424,832 floats = 9.7 MB

typedef __attribute__((ext_vector_type(8))) short short8;   // 8 bf16 (4 VGPRs)
typedef __attribute__((ext_vector_type(4))) float f32x4;

__device__ __forceinline__ float rlane(float x, int l) {
    return __int_as_float(__builtin_amdgcn_readlane(__float_as_int(x), l));
}

// ---------------------------------------------------------------------------
// K1: batched 32x32 SPD solve, v_n = oc_n^{-1} mu_n. One wave per matrix;
// lane c owns column c (c=32 -> rhs). ROUND-6: R4 profile showed VGPR=24 +
// scratch (50us vs 7us floor): #pragma unroll silently failed on the j-loop,
// leaving col[j] dynamically indexed -> forced to scratch. Template-recursive
// GJ makes J a compile-time constant -> static register indexing guaranteed.
// ---------------------------------------------------------------------------
template<int J>
struct GJ {
    static __device__ __forceinline__ void run(float (&col)[32]) {
        const float piv  = rlane(col[J], J);
        const float pinv = 1.0f / piv;
        col[J] *= pinv;
        #pragma unroll
        for (int i = 0; i < 32; ++i) {
            if (i == J) continue;
            const float fi = rlane(col[i], J);
            col[i] = fmaf(-fi, col[J], col[i]);
        }
        GJ<J + 1>::run(col);
    }
};
template<> struct GJ<32> {
    static __device__ __forceinline__ void run(float (&)[32]) {}
};

__global__ __launch_bounds__(256, 1) void solve_kernel(const float* __restrict__ oc,
                                                       const float* __restrict__ mu,
                                                       float* __restrict__ v) {
    const int lane = threadIdx.x & 63;
    const int wid  = threadIdx.x >> 6;
    const int idx  = blockIdx.x * 4 + wid;
    const int c = (lane < 32) ? lane : 32;

    float col[32];
    #pragma unroll
    for (int i = 0; i < 32; ++i) {
        col[i] = (c < 32) ? oc[idx * 1024 + i * 32 + c]
                          : mu[idx * 32 + i];
    }

    GJ<0>::run(col);

    float res = 0.0f;
    #pragma unroll
    for (int i = 0; i < 32; ++i) {
        const float xi = rlane(col[i], 32);
        if (lane == i) res = xi;
    }
    if (lane < 32) v[idx * 32 + lane] = res;
}

// ---------------------------------------------------------------------------
// K0 (after solve): fused transposes.
//  blocks 0..1023:    W (4096x256) -> Wt (256x4096), masked at WEPS
//  blocks 1024..1151: v (4096x32)  -> vT (32x4096)   (k-major for MFMA staging)
// ---------------------------------------------------------------------------
__global__ __launch_bounds__(256) void transpose_fused(const float* __restrict__ W,
                                                       const float* __restrict__ v,
                                                       float* __restrict__ Wt,
                                                       float* __restrict__ vT) {
    __shared__ float tb[32][33];
    const int x = threadIdx.x & 31;
    const int y = threadIdx.x >> 5;          // 0..7
    const int bid = blockIdx.x;
    if (bid < 1024) {
        const int n0 = (bid & 127) * 32;
        const int m0 = (bid >> 7) * 32;
        #pragma unroll
        for (int r = 0; r < 4; ++r) {
            const int n = y + 8 * r;
            float w = W[(size_t)(n0 + n) * 256 + m0 + x];
            tb[n][x] = (w >= WEPS) ? w : 0.0f;
        }
        __syncthreads();
        #pragma unroll
        for (int r = 0; r < 4; ++r) {
            const int mm = y + 8 * r;
            Wt[(size_t)(m0 + mm) * 4096 + n0 + x] = tb[x][mm];
        }
    } else {
        const int n0 = (bid - 1024) * 32;
        #pragma unroll
        for (int r = 0; r < 4; ++r) {
            const int n = y + 8 * r;
            tb[n][x] = v[(size_t)(n0 + n) * 32 + x];
        }
        __syncthreads();
        #pragma unroll
        for (int r = 0; r < 4; ++r) {
            const int kk = y + 8 * r;
            vT[(size_t)kk * 4096 + n0 + x] = tb[x][kk];
        }
    }
}

// ---------------------------------------------------------------------------
// K2 (ROUND-6 MFMA rewrite): per (m,p) block (p = quarter of n), compute
//   S2 = sum_n w v v^T  via  u = sqrt(w) v,  S2 = u^T u  (rank-4096, MFMA)
// u split hi/lo bf16 (RTZ): S2 ~= Uh^T Uh + (Uh^T Ul) + (Uh^T Ul)^T.
// Each of 4 waves owns 256 n's (wave-private LDS, zero barriers in main loop):
//   round (64 n): fp32 vT load -> *sqrt(w) -> hi/lo split -> k-major LDS
//   (row stride 36 dw: 4(k+g)+d banks -> uniform, no extra conflict),
//   then 2 chunks x 8 mfma_f32_16x16x32_bf16 (4 quadrants hh + 4 cross).
// A-frag layout (m120): A[m=lane&15][k=(lane>>4)*8+j]; C/D (m89):
// col=lane&15, row=(lane>>4)*4+reg. B assumed mirror of A; for this
// symmetric product a transposed-B error self-cancels (hh sym, cross D+D^T).
// Epilogue: per-wave scatter to LDS (+transpose pass for D^T), cross-wave
// sum, one record per (m,p) -> combine unchanged.
// ---------------------------------------------------------------------------
__global__ __launch_bounds__(256, 3) void partial_kernel(const float* __restrict__ Wt,
                                                         const float* __restrict__ vT,
                                                         float* __restrict__ wsout) {
    const int m = blockIdx.x >> 2;
    const int p = blockIdx.x & 3;
    const int t = threadIdx.x;
    const int lane = t & 63;
    const int wv   = t >> 6;     // wave id 0..3

    __shared__ unsigned ubuf[4][2][32 * 36];  // [wave][hi/lo][k*36 + n/2] : 36,864 B
    __shared__ float swbuf[1024];             // sqrt(w) for this (m,p)
    __shared__ float zred[256];
    __shared__ float s1buf[32];

    // ---- stage w: sqrt, Z, count ----
    const float4 wv4 = reinterpret_cast<const float4*>(Wt + (size_t)m * 4096 + p * 1024)[t];
    float zacc = wv4.x + wv4.y + wv4.z + wv4.w;
    float cacc = (wv4.x >= WEPS ? 1.f : 0.f) + (wv4.y >= WEPS ? 1.f : 0.f)
               + (wv4.z >= WEPS ? 1.f : 0.f) + (wv4.w >= WEPS ? 1.f : 0.f);
    reinterpret_cast<float4*>(swbuf)[t] =
        make_float4(sqrtf(wv4.x), sqrtf(wv4.y), sqrtf(wv4.z), sqrtf(wv4.w));
    if (t < 32) s1buf[t] = 0.0f;
    __syncthreads();

    f32x4 Chh[4], Chl[4];
    #pragma unroll
    for (int q = 0; q < 4; ++q) {
        Chh[q] = (f32x4){0.f, 0.f, 0.f, 0.f};
        Chl[q] = (f32x4){0.f, 0.f, 0.f, 0.f};
    }
    float s1acc[4] = {0.f, 0.f, 0.f, 0.f};

    const int krow = lane >> 3;        // 0..7
    const int nsub = (lane & 7) * 4;   // 0..28

    for (int rnd = 0; rnd < 4; ++rnd) {
        const int nloc0 = wv * 256 + rnd * 64;   // block-local n base of this wave-round

        // ---- conversion: 64 n x 32 k, fp32 -> u -> bf16 hi/lo in LDS ----
        #pragma unroll
        for (int it = 0; it < 8; ++it) {
            const int k  = krow + 8 * (it & 3);
            const int nn = nsub + 32 * (it >> 2);
            const float4 v4 = *reinterpret_cast<const float4*>(
                vT + (size_t)k * 4096 + p * 1024 + nloc0 + nn);
            const float4 s4 = *reinterpret_cast<const float4*>(&swbuf[nloc0 + nn]);
            const float ux = v4.x * s4.x, uy = v4.y * s4.y;
            const float uz = v4.z * s4.z, uw = v4.w * s4.w;
            const unsigned bx = __float_as_uint(ux), by = __float_as_uint(uy);
            const unsigned bz = __float_as_uint(uz), bw = __float_as_uint(uw);
            const unsigned hi01 = __builtin_amdgcn_perm(by, bx, 0x07060302u);
            const unsigned hi23 = __builtin_amdgcn_perm(bw, bz, 0x07060302u);
            const float lx = ux - __uint_as_float(bx & 0xFFFF0000u);
            const float ly = uy - __uint_as_float(by & 0xFFFF0000u);
            const float lz = uz - __uint_as_float(bz & 0xFFFF0000u);
            const float lw = uw - __uint_as_float(bw & 0xFFFF0000u);
            const unsigned lo01 = __builtin_amdgcn_perm(__float_as_uint(ly), __float_as_uint(lx), 0x07060302u);
            const unsigned lo23 = __builtin_amdgcn_perm(__float_as_uint(lw), __float_as_uint(lz), 0x07060302u);
            const int dwi = k * 36 + (nn >> 1);
            *reinterpret_cast<uint2*>(&ubuf[wv][0][dwi]) = make_uint2(hi01, hi23);
            *reinterpret_cast<uint2*>(&ubuf[wv][1][dwi]) = make_uint2(lo01, lo23);
            // S1 += w*v = sw*u
            s1acc[it & 3] += ux * s4.x + uy * s4.y + uz * s4.z + uw * s4.w;
        }

        // ---- MFMA: 2 chunks of 32 n ----
        #pragma unroll
        for (int c2 = 0; c2 < 2; ++c2) {
            const int ndw = (c2 * 32 + (lane >> 4) * 8) >> 1;
            const int r0 = (lane & 15) * 36 + ndw;
            const int r1 = r0 + 16 * 36;
            const short8 h0 = *reinterpret_cast<const short8*>(&ubuf[wv][0][r0]);
            const short8 h1 = *reinterpret_cast<const short8*>(&ubuf[wv][0][r1]);
            const short8 l0 = *reinterpret_cast<const short8*>(&ubuf[wv][1][r0]);
            const short8 l1 = *reinterpret_cast<const short8*>(&ubuf[wv][1][r1]);
            Chh[0] = __builtin_amdgcn_mfma_f32_16x16x32_bf16(h0, h0, Chh[0], 0, 0, 0);
            Chh[1] = __builtin_amdgcn_mfma_f32_16x16x32_bf16(h0, h1, Chh[1], 0, 0, 0);
            Chh[2] = __builtin_amdgcn_mfma_f32_16x16x32_bf16(h1, h0, Chh[2], 0, 0, 0);
            Chh[3] = __builtin_amdgcn_mfma_f32_16x16x32_bf16(h1, h1, Chh[3], 0, 0, 0);
            Chl[0] = __builtin_amdgcn_mfma_f32_16x16x32_bf16(h0, l0, Chl[0], 0, 0, 0);
            Chl[1] = __builtin_amdgcn_mfma_f32_16x16x32_bf16(h0, l1, Chl[1], 0, 0, 0);
            Chl[2] = __builtin_amdgcn_mfma_f32_16x16x32_bf16(h1, l0, Chl[2], 0, 0, 0);
            Chl[3] = __builtin_amdgcn_mfma_f32_16x16x32_bf16(h1, l1, Chl[3], 0, 0, 0);
        }
    }

    // ---- S1 reduce: 8 consecutive lanes share k ----
    #pragma unroll
    for (int j = 0; j < 4; ++j) {
        float r = s1acc[j];
        r += __shfl_xor(r, 1);
        r += __shfl_xor(r, 2);
        r += __shfl_xor(r, 4);
        if ((lane & 7) == 0) atomicAdd(&s1buf[krow + 8 * j], r);
    }
    __syncthreads();

    // ---- epilogue: scatter quadrants to wave-private LDS, add D^T ----
    float* redw = reinterpret_cast<float*>(&ubuf[wv][0][0]);  // 1024 of 1152 dw
    #pragma unroll
    for (int q = 0; q < 4; ++q) {
        const int I = q >> 1, J = q & 1;
        #pragma unroll
        for (int r = 0; r < 4; ++r) {
            const int a = I * 16 + (lane >> 4) * 4 + r;
            const int b = J * 16 + (lane & 15);
            redw[a * 32 + b] = Chh[q][r] + Chl[q][r];
        }
    }
    __syncthreads();
    #pragma unroll
    for (int q = 0; q < 4; ++q) {
        const int I = q >> 1, J = q & 1;
        #pragma unroll
        for (int r = 0; r < 4; ++r) {
            const int a = I * 16 + (lane >> 4) * 4 + r;
            const int b = J * 16 + (lane & 15);
            redw[b * 32 + a] += Chl[q][r];
        }
    }
    __syncthreads();

    // ---- cross-wave sum + write record ----
    const size_t base = (size_t)(m * 4 + p) * PART_STRIDE;
    float o0 = 0.f, o1 = 0.f, o2 = 0.f, o3 = 0.f;
    #pragma unroll
    for (int ww = 0; ww < 4; ++ww) {
        const float4 x = *reinterpret_cast<const float4*>(
            &reinterpret_cast<float*>(&ubuf[ww][0][0])[t * 4]);
        o0 += x.x; o1 += x.y; o2 += x.z; o3 += x.w;
    }
    *reinterpret_cast<float4*>(&wsout[base + t * 4]) = make_float4(o0, o1, o2, o3);

    // ---- Z / count reductions ----
    zred[t] = zacc; __syncthreads();
    #pragma unroll
    for (int s = 128; s > 0; s >>= 1) {
        if (t < s) zred[t] += zred[t + s];
        __syncthreads();
    }
    if (t == 0) wsout[base + 1056] = zred[0];
    __syncthreads();
    zred[t] = cacc; __syncthreads();
    #pragma unroll
    for (int s = 128; s > 0; s >>= 1) {
        if (t < s) zred[t] += zred[t + s];
        __syncthreads();
    }
    if (t == 0) wsout[base + 1057] = zred[0];
    if (t < 32) wsout[base + 1024 + t] = s1buf[t];
}

// ---------------------------------------------------------------------------
// K3: combine. One block per m.
//   G = op^T op ; psi = tr(G S2)/Z - vbar^T G vbar ; gate count>=2
// ---------------------------------------------------------------------------
__global__ __launch_bounds__(256) void combine_kernel(const float* __restrict__ op,
                                                      const float* __restrict__ ws,
                                                      float* __restrict__ out) {
    const int m = blockIdx.x;
    const int t = threadIdx.x;

    __shared__ float omg[32 * 33];
    __shared__ float vbar[32];
    __shared__ float red[256];

    #pragma unroll
    for (int i = 0; i < 4; ++i) {
        const int g = t + 256 * i;
        const int r = g >> 5, cc = g & 31;
        omg[r * 33 + cc] = op[(size_t)m * 1024 + g];
    }

    const size_t mb = (size_t)m * 4 * PART_STRIDE;
    float Z = 0.0f, cnt = 0.0f, s1 = 0.0f;
    float s2[4] = {0.f, 0.f, 0.f, 0.f};
    #pragma unroll
    for (int p2 = 0; p2 < 4; ++p2) {
        const size_t bp = mb + (size_t)p2 * PART_STRIDE;
        Z   += ws[bp + 1056];
        cnt += ws[bp + 1057];
        if (t < 32) s1 += ws[bp + 1024 + t];
        const float4 sp = *reinterpret_cast<const float4*>(&ws[bp + t * 4]);
        s2[0] += sp.x; s2[1] += sp.y; s2[2] += sp.z; s2[3] += sp.w;
    }
    const float invZ = 1.0f / fmaxf(Z, 1e-30f);
    if (t < 32) vbar[t] = s1 * invZ;
    __syncthreads();

    const int k  = t >> 3;
    const int l0 = (t & 7) * 4;
    float G[4] = {0.f, 0.f, 0.f, 0.f};
    #pragma unroll
    for (int i = 0; i < 32; ++i) {
        const float ok = omg[i * 33 + k];
        #pragma unroll
        for (int q = 0; q < 4; ++q) G[q] = fmaf(ok, omg[i * 33 + l0 + q], G[q]);
    }

    const float vk = vbar[k];
    float val = 0.0f;
    #pragma unroll
    for (int q = 0; q < 4; ++q)
        val += G[q] * (s2[q] * invZ - vk * vbar[l0 + q]);

    red[t] = val; __syncthreads();
    #pragma unroll
    for (int s = 128; s > 0; s >>= 1) {
        if (t < s) red[t] += red[t + s];
        __syncthreads();
    }
    if (t == 0) out[m] = (cnt >= 1.5f) ? red[0] : 0.0f;
}

// ---------------------------------------------------------------------------
extern "C" void kernel_launch(void* const* d_in, const int* in_sizes, int n_in,
                              void* d_out, int out_size, void* d_ws, size_t ws_size,
                              hipStream_t stream) {
    const float* W  = (const float*)d_in[0];  // (4096, 256)
    const float* mu = (const float*)d_in[1];  // (4096, 32)
    const float* oc = (const float*)d_in[2];  // (4096, 32, 32)
    const float* op = (const float*)d_in[3];  // (256, 32, 32)
    float* out = (float*)d_out;               // (256,)
    float* ws  = (float*)d_ws;

    solve_kernel<<<1024, 256, 0, stream>>>(oc, mu, ws + V_OFF);
    transpose_fused<<<1152, 256, 0, stream>>>(W, ws + V_OFF, ws + WT_OFF, ws + VT_OFF);
    partial_kernel<<<1024, 256, 0, stream>>>(ws + WT_OFF, ws + VT_OFF, ws);
    combine_kernel<<<256, 256, 0, stream>>>(op, ws, out);
}